// Round 12
// baseline (566.325 us; speedup 1.0000x reference)
//
#include <hip/hip_runtime.h>
#include <hip/hip_bf16.h>
#include <math.h>

#define NN 8192
#define DD 512
#define INV_T 14.285714285714286f   // 1/0.07 ; also the logits_max (diagonal) value

typedef __attribute__((ext_vector_type(8))) short s16x8;  // 8 bf16 = 4 VGPRs
typedef __attribute__((ext_vector_type(4))) float f32x4;
typedef __attribute__((ext_vector_type(4))) int   i32x4;

__device__ __forceinline__ unsigned short f32_to_bf16(float f) {
  unsigned int u = __float_as_uint(f);
  u += 0x7FFFu + ((u >> 16) & 1u);   // round-to-nearest-even
  return (unsigned short)(u >> 16);
}

__device__ __forceinline__ void async16(const void* g, void* l) {
  // 16B-wide global->LDS DMA; LDS dest must be wave-uniform base + lane*16
  __builtin_amdgcn_global_load_lds((__attribute__((address_space(1))) void*)(void*)g,
                                   (__attribute__((address_space(3))) void*)l,
                                   16, 0, 0);
}

// ---------------- Kernel A: normalize rows, emit bf16 (+ zero accumulators) ----
__global__ __launch_bounds__(256) void normalize_kernel(const float* __restrict__ f,
                                                        unsigned short* __restrict__ fnb,
                                                        float* __restrict__ acc) {
  // fold the 96KB accumulator memset in: 96 blocks x 256 floats
  if (blockIdx.x < 96) acc[blockIdx.x * 256 + threadIdx.x] = 0.f;

  const int wave = threadIdx.x >> 6;
  const int lane = threadIdx.x & 63;
  const int row  = blockIdx.x * 4 + wave;
  const float* src = f + (size_t)row * DD + lane * 8;
  float4 v0 = *(const float4*)src;
  float4 v1 = *(const float4*)(src + 4);
  float ss = v0.x*v0.x + v0.y*v0.y + v0.z*v0.z + v0.w*v0.w
           + v1.x*v1.x + v1.y*v1.y + v1.z*v1.z + v1.w*v1.w;
  #pragma unroll
  for (int o = 32; o; o >>= 1) ss += __shfl_xor(ss, o);
  const float r = 1.0f / fmaxf(sqrtf(ss), 1e-8f);
  ushort4 a, b;
  a.x = f32_to_bf16(v0.x * r); a.y = f32_to_bf16(v0.y * r);
  a.z = f32_to_bf16(v0.z * r); a.w = f32_to_bf16(v0.w * r);
  b.x = f32_to_bf16(v1.x * r); b.y = f32_to_bf16(v1.y * r);
  b.z = f32_to_bf16(v1.z * r); b.w = f32_to_bf16(v1.w * r);
  unsigned short* dst = fnb + (size_t)row * DD + lane * 8;
  *(ushort4*)dst = a;
  *(ushort4*)(dst + 4) = b;
}

// ---------------- Kernel B: single fused kernel ----------------
// R12 = R11 (best: 545-550us) with ONE change: mask loads nontemporal ->
// NORMAL. R9/R11 FETCH (385MB < 524MB mandatory mask bytes) proves L3
// retains ~140MB of masks across bench replays DESPITE nt marking the lines
// evict-first; normal loads let the 256MB Infinity Cache keep more of the
// 512MB stream warm between replays. (R10 tested this confounded with the
// fence regression — this is the clean single-variable read.) Everything
// else byte-identical to R11: dbuf GEMM with one __syncthreads/iter,
// XCD-swizzled block ids, direct int4 mask epilogue, LDS sacc, one global
// atomic batch at the end.
__global__ __launch_bounds__(256, 3) void fused_kernel(const unsigned short* __restrict__ fnb,
                                                       const int* __restrict__ posm,
                                                       const int* __restrict__ negm,
                                                       float* __restrict__ Spos,
                                                       float* __restrict__ Sneg,
                                                       float* __restrict__ Pcnt) {
  // XCD-aware swizzle, then decode compact triangular id -> (bi, bj), bi<=bj
  const int bid = (blockIdx.x & 7) * 260 + (blockIdx.x >> 3);   // 2080 = 8*260
  int bi = (int)(64.5 - sqrt(64.5 * 64.5 - 2.0 * (double)bid));
  while (64 * bi - bi * (bi - 1) / 2 > bid) --bi;
  while (64 * (bi + 1) - (bi + 1) * bi / 2 <= bid) ++bi;
  const int bj = bi + (bid - (64 * bi - bi * (bi - 1) / 2));
  const int I = bi * 128;
  const int J = bj * 128;
  const bool offdiag = (bi != bj);

  const int tid  = threadIdx.x;
  const int wave = tid >> 6;
  const int lane = tid & 63;
  const int wm = wave >> 1;            // 0..1 row half
  const int wn = wave & 1;             // 0..1 col half
  const int q   = lane >> 4;           // 0..3
  const int c16 = lane & 15;           // 0..15

  __shared__ alignas(16) unsigned short lA[2][128 * 32];   // double-buffered
  __shared__ alignas(16) unsigned short lB[2][128 * 32];
  __shared__ float sacc[2][128][3];    // [panel][row][Spos,Sneg,Pcnt]
  for (int t = tid; t < 2 * 128 * 3; t += 256) ((float*)sacc)[t] = 0.f;

  // ---- GEMM: dbuf, one barrier per iteration ----
  f32x4 acc[4][4];
  const f32x4 z4 = {0.f, 0.f, 0.f, 0.f};
  #pragma unroll
  for (int mt = 0; mt < 4; ++mt)
    #pragma unroll
    for (int nt = 0; nt < 4; ++nt) acc[mt][nt] = z4;

  const int fidx0 = tid;
  // prologue: stage tile 0 into buffer 0
  #pragma unroll
  for (int c = 0; c < 2; ++c) {
    const int fidx = tid + c * 256;        // 0..511 16B-chunks
    const int L    = fidx >> 2;            // LDS row 0..127
    const int p    = fidx & 3;
    const int csrc = (p ^ ((L >> 1) & 3)) & 3;     // chunk XOR swizzle
    async16(fnb + (size_t)(I + L) * DD + csrc * 8, (char*)&lA[0][0] + fidx * 16);
    const int gB = 4 * (L & 31) + (L >> 5);        // inverse of L(brow)
    async16(fnb + (size_t)(J + gB) * DD + csrc * 8, (char*)&lB[0][0] + fidx * 16);
  }
  __syncthreads();

  int cur = 0;
  for (int kk = 0; kk < DD / 32; ++kk) {
    // issue NEXT tile's staging first — covered by this tile's reads+MFMA
    if (kk < DD / 32 - 1) {
      const int k0 = (kk + 1) * 32;
      const int nb = cur ^ 1;
      #pragma unroll
      for (int c = 0; c < 2; ++c) {
        const int fidx = fidx0 + c * 256;
        const int L    = fidx >> 2;
        const int p    = fidx & 3;
        const int csrc = (p ^ ((L >> 1) & 3)) & 3;
        async16(fnb + (size_t)(I + L) * DD + k0 + csrc * 8, (char*)&lA[nb][0] + fidx * 16);
        const int gB = 4 * (L & 31) + (L >> 5);
        async16(fnb + (size_t)(J + gB) * DD + k0 + csrc * 8, (char*)&lB[nb][0] + fidx * 16);
      }
    }
    __builtin_amdgcn_sched_barrier(0);   // stage-issue stays before frag reads

    s16x8 aF[4], bF[4];
    #pragma unroll
    for (int t = 0; t < 4; ++t) {
      const int arow = wm * 64 + t * 16 + c16;
      const int apos = (q ^ ((arow >> 1) & 3)) & 3;
      aF[t] = *(const s16x8*)((const char*)&lA[cur][0] + arow * 64 + apos * 16);
      // want global row brow = wn*64 + 4*c16 + t  ->  LDS row L(brow)
      const int Lb = (wn * 16 + c16) | (t << 5);
      const int bpos = (q ^ ((Lb >> 1) & 3)) & 3;
      bF[t] = *(const s16x8*)((const char*)&lB[cur][0] + Lb * 64 + bpos * 16);
    }
    #pragma unroll
    for (int mt = 0; mt < 4; ++mt)
      #pragma unroll
      for (int nt = 0; nt < 4; ++nt)
        acc[mt][nt] = __builtin_amdgcn_mfma_f32_16x16x32_bf16(aF[mt], bF[nt], acc[mt][nt], 0, 0, 0);

    __syncthreads();   // drain covers NEXT tile's staging; protects buffers
    cur ^= 1;
  }

  // ---- epilogue (direct mask epilogue; NORMAL cacheable loads) ----
  // acc[mt][nt][r] = sim[I + wm*64 + mt*16 + q*4 + r][J + wn*64 + 4*c16 + nt]
  #pragma unroll
  for (int mt = 0; mt < 4; ++mt)
    #pragma unroll
    for (int nt = 0; nt < 4; ++nt)
      #pragma unroll
      for (int r = 0; r < 4; ++r)
        acc[mt][nt][r] = __expf(acc[mt][nt][r] * INV_T - INV_T);

  const bool hasdiag = (bi == bj) && (wm == wn);
  const int cb = wn * 64 + 4 * c16;            // local col base (this lane's int4)

  // direct pass: rows I.., cols J.. ; 1KB/wave-instr coalesced int4 loads
  #pragma unroll
  for (int mt = 0; mt < 4; ++mt) {
    const int rl = wm * 64 + mt * 16 + q * 4;  // local row base
    i32x4 pv[4], nv[4];
    #pragma unroll
    for (int r = 0; r < 4; ++r) {
      const size_t off = (size_t)(I + rl + r) * NN + J + cb;
      pv[r] = *(const i32x4*)(posm + off);
      nv[r] = *(const i32x4*)(negm + off);
    }
    #pragma unroll
    for (int r = 0; r < 4; ++r) {
      float dsp = 0.f, dsn = 0.f, dpc = 0.f;
      #pragma unroll
      for (int nt = 0; nt < 4; ++nt) {
        float pf = (float)pv[r][nt];
        float nf = (float)nv[r][nt];
        if (hasdiag && (rl + r == cb + nt)) { pf = 0.f; nf = 0.f; }  // self-contrast diag
        const float e = acc[mt][nt][r];
        dsp = fmaf(e, pf, dsp);
        dsn = fmaf(e, nf, dsn);
        dpc += pf;
      }
      #pragma unroll
      for (int o = 1; o <= 8; o <<= 1) {
        dsp += __shfl_xor(dsp, o);
        dsn += __shfl_xor(dsn, o);
        dpc += __shfl_xor(dpc, o);
      }
      if (c16 == 0) {   // LDS atomics: lgkmcnt only
        atomicAdd(&sacc[0][rl + r][0], dsp);
        atomicAdd(&sacc[0][rl + r][1], dsn);
        atomicAdd(&sacc[0][rl + r][2], dpc);
      }
    }
  }

  // transposed pass: sim(col,row) == sim(row,col); rows J.., cols I..
  if (offdiag) {
    #pragma unroll
    for (int nt = 0; nt < 4; ++nt) {
      const int trl = cb + nt;                 // local row in J-panel
      i32x4 pv[4], nv[4];
      #pragma unroll
      for (int mt = 0; mt < 4; ++mt) {
        const size_t off = (size_t)(J + trl) * NN + I + wm * 64 + mt * 16 + q * 4;
        pv[mt] = *(const i32x4*)(posm + off);
        nv[mt] = *(const i32x4*)(negm + off);
      }
      float ts = 0.f, tn = 0.f, tp = 0.f;
      #pragma unroll
      for (int mt = 0; mt < 4; ++mt) {
        #pragma unroll
        for (int r = 0; r < 4; ++r) {
          const float e = acc[mt][nt][r];
          ts = fmaf(e, (float)pv[mt][r], ts);
          tn = fmaf(e, (float)nv[mt][r], tn);
          tp += (float)pv[mt][r];
        }
      }
      ts += __shfl_xor(ts, 16); ts += __shfl_xor(ts, 32);
      tn += __shfl_xor(tn, 16); tn += __shfl_xor(tn, 32);
      tp += __shfl_xor(tp, 16); tp += __shfl_xor(tp, 32);
      if (q == 0) {
        atomicAdd(&sacc[1][trl][0], ts);
        atomicAdd(&sacc[1][trl][1], tn);
        atomicAdd(&sacc[1][trl][2], tp);
      }
    }
  }

  __syncthreads();

  // one batch of global atomics at the very end; nothing waits on them
  const int r = tid & 127;
  if (tid < 128) {
    atomicAdd(&Spos[I + r], sacc[0][r][0]);
    atomicAdd(&Sneg[I + r], sacc[0][r][1]);
    atomicAdd(&Pcnt[I + r], sacc[0][r][2]);
  } else if (offdiag) {
    atomicAdd(&Spos[J + r], sacc[1][r][0]);
    atomicAdd(&Sneg[J + r], sacc[1][r][1]);
    atomicAdd(&Pcnt[J + r], sacc[1][r][2]);
  }
}

// ---------------- Kernel C: finalize ----------------
__global__ __launch_bounds__(256) void finalize_kernel(const float* __restrict__ Spos,
                                                       const float* __restrict__ Sneg,
                                                       const float* __restrict__ Pcnt,
                                                       float* __restrict__ out) {
  float local = 0.f;
  for (int i = threadIdx.x; i < NN; i += 256) {
    const float sp = Spos[i], sn = Sneg[i], pc = Pcnt[i];
    const float card = (pc == 0.f) ? 1.f : pc;
    local += (logf(sn) * pc - sp) / card;
  }
  #pragma unroll
  for (int o = 32; o; o >>= 1) local += __shfl_xor(local, o);
  __shared__ float red[4];
  if ((threadIdx.x & 63) == 0) red[threadIdx.x >> 6] = local;
  __syncthreads();
  if (threadIdx.x == 0)
    out[0] = (red[0] + red[1] + red[2] + red[3]) * (1.0f / (float)NN);
}

extern "C" void kernel_launch(void* const* d_in, const int* in_sizes, int n_in,
                              void* d_out, int out_size, void* d_ws, size_t ws_size,
                              hipStream_t stream) {
  const float* feat = (const float*)d_in[0];
  const int* posm   = (const int*)d_in[1];
  const int* negm   = (const int*)d_in[2];
  float* out = (float*)d_out;

  char* ws = (char*)d_ws;
  unsigned short* fnb = (unsigned short*)ws;                 // 8 MB
  float* Spos = (float*)(ws + (size_t)8 * 1024 * 1024);
  float* Sneg = Spos + NN;
  float* Pcnt = Sneg + NN;

  normalize_kernel<<<NN / 4, 256, 0, stream>>>(feat, fnb, Spos);
  fused_kernel<<<2080, 256, 0, stream>>>(fnb, posm, negm, Spos, Sneg, Pcnt);
  finalize_kernel<<<1, 256, 0, stream>>>(Spos, Sneg, Pcnt, out);
}

// Round 13
// 549.423 us; speedup vs baseline: 1.0308x; 1.0308x over previous
//
#include <hip/hip_runtime.h>
#include <hip/hip_bf16.h>
#include <math.h>

#define NN 8192
#define DD 512
#define INV_T 14.285714285714286f   // 1/0.07 ; also the logits_max (diagonal) value

typedef __attribute__((ext_vector_type(8))) short s16x8;  // 8 bf16 = 4 VGPRs
typedef __attribute__((ext_vector_type(4))) float f32x4;
typedef __attribute__((ext_vector_type(4))) int   i32x4;

__device__ __forceinline__ unsigned short f32_to_bf16(float f) {
  unsigned int u = __float_as_uint(f);
  u += 0x7FFFu + ((u >> 16) & 1u);   // round-to-nearest-even
  return (unsigned short)(u >> 16);
}

__device__ __forceinline__ void async16(const void* g, void* l) {
  // 16B-wide global->LDS DMA; LDS dest must be wave-uniform base + lane*16
  __builtin_amdgcn_global_load_lds((__attribute__((address_space(1))) void*)(void*)g,
                                   (__attribute__((address_space(3))) void*)l,
                                   16, 0, 0);
}

// ---------------- Kernel A: normalize rows, emit bf16 (+ zero accumulators) ----
__global__ __launch_bounds__(256) void normalize_kernel(const float* __restrict__ f,
                                                        unsigned short* __restrict__ fnb,
                                                        float* __restrict__ acc) {
  // fold the 96KB accumulator memset in: 96 blocks x 256 floats
  if (blockIdx.x < 96) acc[blockIdx.x * 256 + threadIdx.x] = 0.f;

  const int wave = threadIdx.x >> 6;
  const int lane = threadIdx.x & 63;
  const int row  = blockIdx.x * 4 + wave;
  const float* src = f + (size_t)row * DD + lane * 8;
  float4 v0 = *(const float4*)src;
  float4 v1 = *(const float4*)(src + 4);
  float ss = v0.x*v0.x + v0.y*v0.y + v0.z*v0.z + v0.w*v0.w
           + v1.x*v1.x + v1.y*v1.y + v1.z*v1.z + v1.w*v1.w;
  #pragma unroll
  for (int o = 32; o; o >>= 1) ss += __shfl_xor(ss, o);
  const float r = 1.0f / fmaxf(sqrtf(ss), 1e-8f);
  ushort4 a, b;
  a.x = f32_to_bf16(v0.x * r); a.y = f32_to_bf16(v0.y * r);
  a.z = f32_to_bf16(v0.z * r); a.w = f32_to_bf16(v0.w * r);
  b.x = f32_to_bf16(v1.x * r); b.y = f32_to_bf16(v1.y * r);
  b.z = f32_to_bf16(v1.z * r); b.w = f32_to_bf16(v1.w * r);
  unsigned short* dst = fnb + (size_t)row * DD + lane * 8;
  *(ushort4*)dst = a;
  *(ushort4*)(dst + 4) = b;
}

// ---------------- Kernel B: single fused kernel ----------------
// R13 = R11 (best: 545-550, nt mask loads RESTORED per R12's clean A/B:
// normal loads cost +45us — nt bypasses L2 allocation, 512MB stream thrashes
// the 4MB per-XCD L2s otherwise) + ONE GEMM change: TRIPLE-buffered staging
// with counted vmcnt (T4). R9's 1-deep dbuf bought only ~4us because iter
// kk's staging is drained by iter kk's own barrier (zero cover). Now: iter
// kk stages tile kk+2; s_waitcnt vmcnt(8) retires only tile kk's 4 loads —
// tiles kk+1/kk+2 stay IN FLIGHT across the raw s_barrier, giving staging
// two full iterations (~2x ds_read+MFMA+barrier) of latency cover. R5
// proved this asm machinery correct on this kernel (it targeted the wrong
// traffic). Wave-uniform control flow -> barrier counts trivially matched.
// Buffer hazard: iter kk overwrites buf (kk+2)%3 == (kk-1)%3, whose readers
// all passed iter kk-1's end-barrier. LDS 51KB -> still 3 blocks/CU.
__global__ __launch_bounds__(256, 3) void fused_kernel(const unsigned short* __restrict__ fnb,
                                                       const int* __restrict__ posm,
                                                       const int* __restrict__ negm,
                                                       float* __restrict__ Spos,
                                                       float* __restrict__ Sneg,
                                                       float* __restrict__ Pcnt) {
  // XCD-aware swizzle, then decode compact triangular id -> (bi, bj), bi<=bj
  const int bid = (blockIdx.x & 7) * 260 + (blockIdx.x >> 3);   // 2080 = 8*260
  int bi = (int)(64.5 - sqrt(64.5 * 64.5 - 2.0 * (double)bid));
  while (64 * bi - bi * (bi - 1) / 2 > bid) --bi;
  while (64 * (bi + 1) - (bi + 1) * bi / 2 <= bid) ++bi;
  const int bj = bi + (bid - (64 * bi - bi * (bi - 1) / 2));
  const int I = bi * 128;
  const int J = bj * 128;
  const bool offdiag = (bi != bj);

  const int tid  = threadIdx.x;
  const int wave = tid >> 6;
  const int lane = tid & 63;
  const int wm = wave >> 1;            // 0..1 row half
  const int wn = wave & 1;             // 0..1 col half
  const int q   = lane >> 4;           // 0..3
  const int c16 = lane & 15;           // 0..15

  __shared__ alignas(16) unsigned short lA[3][128 * 32];   // triple-buffered
  __shared__ alignas(16) unsigned short lB[3][128 * 32];
  __shared__ float sacc[2][128][3];    // [panel][row][Spos,Sneg,Pcnt]
  for (int t = tid; t < 2 * 128 * 3; t += 256) ((float*)sacc)[t] = 0.f;

  // ---- GEMM: tri-buf, counted vmcnt, 2 raw barriers per iteration ----
  f32x4 acc[4][4];
  const f32x4 z4 = {0.f, 0.f, 0.f, 0.f};
  #pragma unroll
  for (int mt = 0; mt < 4; ++mt)
    #pragma unroll
    for (int nt = 0; nt < 4; ++nt) acc[mt][nt] = z4;

  // per-thread staging geometry (R0-proven swizzle, 0 conflicts):
  // chunk ids tid and tid+256; 4 async16 (wave-level vmem ops) per tile.
  #define STAGE_TILE(kt, buf)                                                   \
    do {                                                                        \
      const int _k0 = (kt) * 32;                                                \
      _Pragma("unroll")                                                         \
      for (int _c = 0; _c < 2; ++_c) {                                          \
        const int _fidx = tid + _c * 256;                                       \
        const int _L    = _fidx >> 2;                                           \
        const int _p    = _fidx & 3;                                            \
        const int _csrc = (_p ^ ((_L >> 1) & 3)) & 3;                           \
        async16(fnb + (size_t)(I + _L) * DD + _k0 + _csrc * 8,                  \
                (char*)&lA[(buf)][0] + _fidx * 16);                             \
        const int _gB = 4 * (_L & 31) + (_L >> 5);                              \
        async16(fnb + (size_t)(J + _gB) * DD + _k0 + _csrc * 8,                 \
                (char*)&lB[(buf)][0] + _fidx * 16);                             \
      }                                                                         \
    } while (0)

  // prologue: tiles 0,1 into buffers 0,1 (8 vmem ops outstanding)
  STAGE_TILE(0, 0);
  STAGE_TILE(1, 1);

  int cb = 0;   // buffer holding tile kk
  int sb = 2;   // buffer to stage tile kk+2 into
  for (int kk = 0; kk < DD / 32; ++kk) {
    if (kk + 2 < DD / 32) STAGE_TILE(kk + 2, sb);
    __builtin_amdgcn_sched_barrier(0);
    // retire ONLY tile kk's 4 loads; deeper tiles stay in flight across the
    // barrier. outstanding: kk<=13 -> 12, kk==14 -> 8, kk==15 -> 4.
    if (kk + 2 < DD / 32)      asm volatile("s_waitcnt vmcnt(8)" ::: "memory");
    else if (kk + 1 < DD / 32) asm volatile("s_waitcnt vmcnt(4)" ::: "memory");
    else                       asm volatile("s_waitcnt vmcnt(0)" ::: "memory");
    __builtin_amdgcn_sched_barrier(0);
    __builtin_amdgcn_s_barrier();        // tile kk fully in LDS for all waves
    __builtin_amdgcn_sched_barrier(0);

    const char* bA = (const char*)&lA[cb][0];
    const char* bB = (const char*)&lB[cb][0];
    s16x8 aF[4], bF[4];
    #pragma unroll
    for (int t = 0; t < 4; ++t) {
      const int arow = wm * 64 + t * 16 + c16;
      const int apos = (q ^ ((arow >> 1) & 3)) & 3;
      aF[t] = *(const s16x8*)(bA + arow * 64 + apos * 16);
      // want global row brow = wn*64 + 4*c16 + t  ->  LDS row L(brow)
      const int Lb = (wn * 16 + c16) | (t << 5);
      const int bpos = (q ^ ((Lb >> 1) & 3)) & 3;
      bF[t] = *(const s16x8*)(bB + Lb * 64 + bpos * 16);
    }
    #pragma unroll
    for (int mt = 0; mt < 4; ++mt)
      #pragma unroll
      for (int nt = 0; nt < 4; ++nt)
        acc[mt][nt] = __builtin_amdgcn_mfma_f32_16x16x32_bf16(aF[mt], bF[nt], acc[mt][nt], 0, 0, 0);

    __builtin_amdgcn_sched_barrier(0);
    __builtin_amdgcn_s_barrier();        // done reading buf cb -> reusable
    __builtin_amdgcn_sched_barrier(0);

    cb = (cb == 2) ? 0 : cb + 1;
    sb = (sb == 2) ? 0 : sb + 1;
  }
  #undef STAGE_TILE

  // ---- epilogue (R11-proven: nontemporal int4 mask loads) ----
  // acc[mt][nt][r] = sim[I + wm*64 + mt*16 + q*4 + r][J + wn*64 + 4*c16 + nt]
  #pragma unroll
  for (int mt = 0; mt < 4; ++mt)
    #pragma unroll
    for (int nt = 0; nt < 4; ++nt)
      #pragma unroll
      for (int r = 0; r < 4; ++r)
        acc[mt][nt][r] = __expf(acc[mt][nt][r] * INV_T - INV_T);

  const bool hasdiag = (bi == bj) && (wm == wn);
  const int cb2 = wn * 64 + 4 * c16;           // local col base (this lane's int4)

  // direct pass: rows I.., cols J.. ; 1KB/wave-instr coalesced int4 loads
  #pragma unroll
  for (int mt = 0; mt < 4; ++mt) {
    const int rl = wm * 64 + mt * 16 + q * 4;  // local row base
    i32x4 pv[4], nv[4];
    #pragma unroll
    for (int r = 0; r < 4; ++r) {
      const size_t off = (size_t)(I + rl + r) * NN + J + cb2;
      pv[r] = __builtin_nontemporal_load((const i32x4*)(posm + off));
      nv[r] = __builtin_nontemporal_load((const i32x4*)(negm + off));
    }
    #pragma unroll
    for (int r = 0; r < 4; ++r) {
      float dsp = 0.f, dsn = 0.f, dpc = 0.f;
      #pragma unroll
      for (int nt = 0; nt < 4; ++nt) {
        float pf = (float)pv[r][nt];
        float nf = (float)nv[r][nt];
        if (hasdiag && (rl + r == cb2 + nt)) { pf = 0.f; nf = 0.f; }  // self-contrast diag
        const float e = acc[mt][nt][r];
        dsp = fmaf(e, pf, dsp);
        dsn = fmaf(e, nf, dsn);
        dpc += pf;
      }
      #pragma unroll
      for (int o = 1; o <= 8; o <<= 1) {
        dsp += __shfl_xor(dsp, o);
        dsn += __shfl_xor(dsn, o);
        dpc += __shfl_xor(dpc, o);
      }
      if (c16 == 0) {   // LDS atomics: lgkmcnt only
        atomicAdd(&sacc[0][rl + r][0], dsp);
        atomicAdd(&sacc[0][rl + r][1], dsn);
        atomicAdd(&sacc[0][rl + r][2], dpc);
      }
    }
  }

  // transposed pass: sim(col,row) == sim(row,col); rows J.., cols I..
  if (offdiag) {
    #pragma unroll
    for (int nt = 0; nt < 4; ++nt) {
      const int trl = cb2 + nt;                // local row in J-panel
      i32x4 pv[4], nv[4];
      #pragma unroll
      for (int mt = 0; mt < 4; ++mt) {
        const size_t off = (size_t)(J + trl) * NN + I + wm * 64 + mt * 16 + q * 4;
        pv[mt] = __builtin_nontemporal_load((const i32x4*)(posm + off));
        nv[mt] = __builtin_nontemporal_load((const i32x4*)(negm + off));
      }
      float ts = 0.f, tn = 0.f, tp = 0.f;
      #pragma unroll
      for (int mt = 0; mt < 4; ++mt) {
        #pragma unroll
        for (int r = 0; r < 4; ++r) {
          const float e = acc[mt][nt][r];
          ts = fmaf(e, (float)pv[mt][r], ts);
          tn = fmaf(e, (float)nv[mt][r], tn);
          tp += (float)pv[mt][r];
        }
      }
      ts += __shfl_xor(ts, 16); ts += __shfl_xor(ts, 32);
      tn += __shfl_xor(tn, 16); tn += __shfl_xor(tn, 32);
      tp += __shfl_xor(tp, 16); tp += __shfl_xor(tp, 32);
      if (q == 0) {
        atomicAdd(&sacc[1][trl][0], ts);
        atomicAdd(&sacc[1][trl][1], tn);
        atomicAdd(&sacc[1][trl][2], tp);
      }
    }
  }

  __syncthreads();

  // one batch of global atomics at the very end; nothing waits on them
  const int r = tid & 127;
  if (tid < 128) {
    atomicAdd(&Spos[I + r], sacc[0][r][0]);
    atomicAdd(&Sneg[I + r], sacc[0][r][1]);
    atomicAdd(&Pcnt[I + r], sacc[0][r][2]);
  } else if (offdiag) {
    atomicAdd(&Spos[J + r], sacc[1][r][0]);
    atomicAdd(&Sneg[J + r], sacc[1][r][1]);
    atomicAdd(&Pcnt[J + r], sacc[1][r][2]);
  }
}

// ---------------- Kernel C: finalize ----------------
__global__ __launch_bounds__(256) void finalize_kernel(const float* __restrict__ Spos,
                                                       const float* __restrict__ Sneg,
                                                       const float* __restrict__ Pcnt,
                                                       float* __restrict__ out) {
  float local = 0.f;
  for (int i = threadIdx.x; i < NN; i += 256) {
    const float sp = Spos[i], sn = Sneg[i], pc = Pcnt[i];
    const float card = (pc == 0.f) ? 1.f : pc;
    local += (logf(sn) * pc - sp) / card;
  }
  #pragma unroll
  for (int o = 32; o; o >>= 1) local += __shfl_xor(local, o);
  __shared__ float red[4];
  if ((threadIdx.x & 63) == 0) red[threadIdx.x >> 6] = local;
  __syncthreads();
  if (threadIdx.x == 0)
    out[0] = (red[0] + red[1] + red[2] + red[3]) * (1.0f / (float)NN);
}

extern "C" void kernel_launch(void* const* d_in, const int* in_sizes, int n_in,
                              void* d_out, int out_size, void* d_ws, size_t ws_size,
                              hipStream_t stream) {
  const float* feat = (const float*)d_in[0];
  const int* posm   = (const int*)d_in[1];
  const int* negm   = (const int*)d_in[2];
  float* out = (float*)d_out;

  char* ws = (char*)d_ws;
  unsigned short* fnb = (unsigned short*)ws;                 // 8 MB
  float* Spos = (float*)(ws + (size_t)8 * 1024 * 1024);
  float* Sneg = Spos + NN;
  float* Pcnt = Sneg + NN;

  normalize_kernel<<<NN / 4, 256, 0, stream>>>(feat, fnb, Spos);
  fused_kernel<<<2080, 256, 0, stream>>>(fnb, posm, negm, Spos, Sneg, Pcnt);
  finalize_kernel<<<1, 256, 0, stream>>>(Spos, Sneg, Pcnt, out);
}